// Round 14
// baseline (181.701 us; speedup 1.0000x reference)
//
#include <hip/hip_runtime.h>

#define BB 8
#define CC 64
#define NN 4096
#define NIC 4            // i-chunks in attn pass
#define JCH 8            // j-chunks in stats pass
#define LOG2E 1.4426950408889634f

typedef float f32x4  __attribute__((ext_vector_type(4)));
typedef float f32x16 __attribute__((ext_vector_type(16)));
typedef _Float16 half8_t __attribute__((ext_vector_type(8)));
typedef int int4v __attribute__((ext_vector_type(4)));

// 32x32x16 f16 MFMA layouts (gfx950):
//   A[m][k]: m = lane&31, k = (lane>>5)*8 + idx   (8 halves)
//   B[k][n]: n = lane&31, k = (lane>>5)*8 + idx
//   C/D:     col = lane&31, row = (reg&3) + 8*(reg>>2) + 4*(lane>>5)
// A and B fragment layouts are IDENTICAL — swapping operand order transposes
// which index (reg vs lane) carries M — exploited in qkv.

// ---------------------------------------------------------------------------
// Kernel A: fused 1x1-conv QKV via MFMA. grid (NN/64, B), block 256 (4 waves).
// x tile staged + f16-converted ONCE; 6 chains split: zg0: f.ot0 f.ot1 g.ot0;
// zg1: h.ot0 h.ot1 g.ot1.
// ---------------------------------------------------------------------------
__global__ __launch_bounds__(256, 2) void qkv_kernel(
    const float* __restrict__ x,
    const float* __restrict__ Wf, const float* __restrict__ bf,
    const float* __restrict__ Wg, const float* __restrict__ bg,
    const float* __restrict__ Wh, const float* __restrict__ bh,
    _Float16* __restrict__ fT, _Float16* __restrict__ gT,
    _Float16* __restrict__ hT)
{
    __shared__ float xbuf[64][68];         // 17.4 KB, stride 68 floats

    const int tid  = threadIdx.x;
    const int lane = tid & 63;
    const int wv   = tid >> 6;
    const int l31  = lane & 31;
    const int q5   = lane >> 5;
    const int st   = wv & 1;               // px-subtile 0/1
    const int zg   = wv >> 1;              // task group
    const int n0   = blockIdx.x * 64;
    const int b    = blockIdx.y;

    {
        const int c = tid >> 2;
        const float* src = x + (size_t)(b * CC + c) * NN + n0 + (tid & 3) * 16;
#pragma unroll
        for (int k = 0; k < 4; ++k)
            *(f32x4*)&xbuf[c][(tid & 3) * 16 + k * 4] = *(const f32x4*)(src + k * 4);
    }
    __syncthreads();

    const int pxl = st * 32 + l31;
    half8_t xf[4];
#pragma unroll
    for (int kc = 0; kc < 4; ++kc) {
        const int kb = kc * 16 + q5 * 8;
        int4v p;
#pragma unroll
        for (int h2 = 0; h2 < 4; ++h2) {
            p[h2] = __builtin_bit_cast(int, __builtin_amdgcn_cvt_pkrtz(
                xbuf[kb + h2 * 2][pxl], xbuf[kb + h2 * 2 + 1][pxl]));
        }
        xf[kc] = __builtin_bit_cast(half8_t, p);
    }

    auto load_wf = [&](const float* W, int ot, half8_t* out) {
        const float* wrow = W + (size_t)(ot * 32 + l31) * CC;
#pragma unroll
        for (int kc = 0; kc < 4; ++kc) {
            const f32x4 w0 = *(const f32x4*)(wrow + kc * 16 + q5 * 8);
            const f32x4 w1 = *(const f32x4*)(wrow + kc * 16 + q5 * 8 + 4);
            int4v p;
            p[0] = __builtin_bit_cast(int, __builtin_amdgcn_cvt_pkrtz(w0[0], w0[1]));
            p[1] = __builtin_bit_cast(int, __builtin_amdgcn_cvt_pkrtz(w0[2], w0[3]));
            p[2] = __builtin_bit_cast(int, __builtin_amdgcn_cvt_pkrtz(w1[0], w1[1]));
            p[3] = __builtin_bit_cast(int, __builtin_amdgcn_cvt_pkrtz(w1[2], w1[3]));
            out[kc] = __builtin_bit_cast(half8_t, p);
        }
    };

    auto store_fg = [&](_Float16* dstT, const float* bias, int ot,
                        const f32x16& acc, float scale) {
        const float bv = bias[ot * 32 + l31];
#pragma unroll
        for (int r = 0; r < 16; ++r) {
            const int prow = (r & 3) + 8 * (r >> 2) + 4 * q5;
            const int n = n0 + st * 32 + prow;
            dstT[(size_t)(b * NN + n) * CC + ot * 32 + l31] =
                (_Float16)((acc[r] + bv) * scale);
        }
    };

    if (zg == 0) {
        half8_t wfa[4], wfb[4], wga[4];
        load_wf(Wf, 0, wfa);
        load_wf(Wf, 1, wfb);
        load_wf(Wg, 0, wga);
        f32x16 a0 = {}, a1 = {}, a2 = {};
#pragma unroll
        for (int kc = 0; kc < 4; ++kc) {
            a0 = __builtin_amdgcn_mfma_f32_32x32x16_f16(xf[kc], wfa[kc], a0, 0, 0, 0);
            a1 = __builtin_amdgcn_mfma_f32_32x32x16_f16(xf[kc], wfb[kc], a1, 0, 0, 0);
            a2 = __builtin_amdgcn_mfma_f32_32x32x16_f16(xf[kc], wga[kc], a2, 0, 0, 0);
        }
        store_fg(fT, bf, 0, a0, LOG2E);
        store_fg(fT, bf, 1, a1, LOG2E);
        store_fg(gT, bg, 0, a2, 1.0f);
    } else {
        half8_t wha[4], whb[4], wgb[4];
        load_wf(Wh, 0, wha);
        load_wf(Wh, 1, whb);
        load_wf(Wg, 1, wgb);
        f32x16 a0 = {}, a1 = {}, a2 = {};
#pragma unroll
        for (int kc = 0; kc < 4; ++kc) {
            a0 = __builtin_amdgcn_mfma_f32_32x32x16_f16(wha[kc], xf[kc], a0, 0, 0, 0);
            a1 = __builtin_amdgcn_mfma_f32_32x32x16_f16(whb[kc], xf[kc], a1, 0, 0, 0);
            a2 = __builtin_amdgcn_mfma_f32_32x32x16_f16(xf[kc], wgb[kc], a2, 0, 0, 0);
        }
        _Float16* hbase = hT + ((size_t)(b * (NN / 32) + (n0 + st * 32) / 32) * CC) * 32;
#pragma unroll
        for (int ot = 0; ot < 2; ++ot) {
            const f32x16& acc = ot ? a1 : a0;
#pragma unroll
            for (int rb = 0; rb < 4; ++rb) {
                const f32x4 b4 = *(const f32x4*)(bh + ot * 32 + rb * 8 + q5 * 4);
#pragma unroll
                for (int k = 0; k < 4; ++k) {
                    const int c = ot * 32 + rb * 8 + q5 * 4 + k;
                    hbase[(size_t)c * 32 + l31] = (_Float16)(acc[rb * 4 + k] + b4[k]);
                }
            }
        }
        store_fg(gT, bg, 1, a2, 1.0f);
    }
}

// ---------------------------------------------------------------------------
// Kernel B: partial row sums of exp2(logits). grid (NN/256, B, JCH), block 256.
// WAVE I-TILE 64 (2 A-frag sets): 16 MFMA share the same 4 ds_read_b128 g
// reads per js — 2x amortization vs the old i-tile-32 version, and half the
// g re-read traffic (1024 blocks x 68 KB). Same j-order per i-row -> l is
// bit-identical to previous rounds.
// ---------------------------------------------------------------------------
__global__ __launch_bounds__(256, 4) void stats_kernel(
    const _Float16* __restrict__ fT, const _Float16* __restrict__ gT,
    float* __restrict__ lpart)
{
    __shared__ _Float16 gbuf[2][64][72];   // stride 72 halves

    const int lane = threadIdx.x & 63;
    const int wv   = threadIdx.x >> 6;
    const int b    = blockIdx.y;
    const int jc   = blockIdx.z;
    const int i0   = blockIdx.x * 256 + wv * 64;
    const int l31  = lane & 31;
    const int q5   = lane >> 5;

    // A-frags for 2 i-tiles, fixed in registers
    half8_t a[2][4];
#pragma unroll
    for (int it = 0; it < 2; ++it) {
        const _Float16* fa = fT + (size_t)(b * NN + i0 + it * 32 + l31) * CC + q5 * 8;
#pragma unroll
        for (int kc = 0; kc < 4; ++kc) a[it][kc] = *(const half8_t*)(fa + kc * 16);
    }

    const _Float16* gchunk = gT + (size_t)(b * NN + jc * (NN / JCH)) * CC;
    const int T = NN / JCH / 64;   // 8 tiles of 64 j

    const int srow = wv * 16 + (lane >> 3);
    const int scol = (lane & 7) * 8;

    {   // stage tile 0
        const half8_t v0 = *(const half8_t*)(gchunk + (size_t)srow * CC + scol);
        const half8_t v1 = *(const half8_t*)(gchunk + (size_t)(srow + 8) * CC + scol);
        *(half8_t*)&gbuf[0][srow][scol] = v0;
        *(half8_t*)&gbuf[0][srow + 8][scol] = v1;
    }
    __syncthreads();

    float la[16], lb[16];
#pragma unroll
    for (int r = 0; r < 16; ++r) { la[r] = 0.f; lb[r] = 0.f; }

    for (int t = 0; t < T; ++t) {
        const int buf = t & 1;
        const bool pf = (t + 1 < T);
        half8_t p0, p1;
        if (pf) {
            const _Float16* src = gchunk + (size_t)((t + 1) * 64 + srow) * CC + scol;
            p0 = *(const half8_t*)(src);
            p1 = *(const half8_t*)(src + 8 * CC);
        }
#pragma unroll
        for (int js = 0; js < 2; ++js) {
            const _Float16* grow = &gbuf[buf][js * 32 + l31][0] + q5 * 8;
            f32x16 s0 = {}, s1 = {};
#pragma unroll
            for (int kc = 0; kc < 4; ++kc) {
                const half8_t bfr = *(const half8_t*)(grow + kc * 16);
                s0 = __builtin_amdgcn_mfma_f32_32x32x16_f16(a[0][kc], bfr, s0, 0, 0, 0);
                s1 = __builtin_amdgcn_mfma_f32_32x32x16_f16(a[1][kc], bfr, s1, 0, 0, 0);
            }
#pragma unroll
            for (int r = 0; r < 16; ++r) {
                la[r] += __builtin_exp2f(s0[r]);
                lb[r] += __builtin_exp2f(s1[r]);
            }
        }
        if (pf) {
            *(half8_t*)&gbuf[buf ^ 1][srow][scol] = p0;
            *(half8_t*)&gbuf[buf ^ 1][srow + 8][scol] = p1;
        }
        __syncthreads();
    }

    // reduce across the 32 j-columns (lanes sharing q5)
#pragma unroll
    for (int r = 0; r < 16; ++r) {
#pragma unroll
        for (int off = 1; off < 32; off <<= 1) {
            la[r] += __shfl_xor(la[r], off);
            lb[r] += __shfl_xor(lb[r], off);
        }
    }

    if (l31 == 0) {
#pragma unroll
        for (int it = 0; it < 2; ++it) {
            const float* l16 = it ? lb : la;
            float* lp = lpart + (size_t)jc * BB * NN + b * NN + i0 + it * 32;
#pragma unroll
            for (int rb = 0; rb < 4; ++rb) {
                f32x4 v;
#pragma unroll
                for (int k = 0; k < 4; ++k) v[k] = l16[rb * 4 + k];
                *(f32x4*)(lp + rb * 8 + q5 * 4) = v;
            }
        }
    }
}

// ---------------------------------------------------------------------------
// Kernel B2: nbias = -log2(sum_jc lpart)
// ---------------------------------------------------------------------------
__global__ __launch_bounds__(256) void rmerge_kernel(
    const float* __restrict__ lpart, float* __restrict__ nbias)
{
    const int idx = blockIdx.x * 256 + threadIdx.x;
    float s = 0.f;
#pragma unroll
    for (int jc = 0; jc < JCH; ++jc) s += lpart[(size_t)jc * BB * NN + idx];
    nbias[idx] = -__builtin_log2f(s);
}

// ---------------------------------------------------------------------------
// Kernel C: partial out chunks. grid (NN/256, B, NIC), block 256.
// R12 structure: wave j-tile 64 (2 bg/acc sets), 1-deep register prefetch.
// ---------------------------------------------------------------------------
__global__ __launch_bounds__(256, 2) void attn_kernel(
    const _Float16* __restrict__ fT, const _Float16* __restrict__ gT,
    const _Float16* __restrict__ hT, const float* __restrict__ nbias,
    _Float16* __restrict__ pout)
{
    __shared__ _Float16 fbuf[2][64][72];   // 18.4 KB
    __shared__ _Float16 hbuf[2][64][72];   // 18.4 KB

    const int lane = threadIdx.x & 63;
    const int wv   = threadIdx.x >> 6;
    const int b    = blockIdx.y;
    const int ic   = blockIdx.z;
    const int l31  = lane & 31;
    const int q5   = lane >> 5;
    const int jbase = blockIdx.x * 256 + wv * 64;

    half8_t bg[2][4];
#pragma unroll
    for (int jt = 0; jt < 2; ++jt) {
        const _Float16* grow = gT + (size_t)(b * NN + jbase + jt * 32 + l31) * CC + q5 * 8;
#pragma unroll
        for (int kc = 0; kc < 4; ++kc) bg[jt][kc] = *(const half8_t*)(grow + kc * 16);
    }

    f32x16 acc[2][2] = {};   // [jt][ct]

    const int ichunk = NN / NIC;           // 1024
    const int ibase  = ic * ichunk;
    const _Float16* fchunk = fT + ((size_t)b * NN + ibase) * CC;
    const _Float16* hchunk = hT + ((size_t)(b * (NN / 32) + ibase / 32) * CC) * 32;
    const float*    nb     = nbias + b * NN + ibase;
    const int T = ichunk / 64;             // 16 iterations

    const int tid    = threadIdx.x;
    const int frow_s = tid >> 2;            // 0..63
    const int fcol_s = (tid & 3) * 16;
    const int hrow_s = tid >> 2;
    const int hcol_s = (tid & 3) * 8;

    {   // stage tile 0
        const half8_t f0 = *(const half8_t*)(fchunk + (size_t)frow_s * CC + fcol_s);
        const half8_t f1 = *(const half8_t*)(fchunk + (size_t)frow_s * CC + fcol_s + 8);
        const half8_t h0 = *(const half8_t*)(hchunk + tid * 8);
        const half8_t h1 = *(const half8_t*)(hchunk + 2048 + tid * 8);
        *(half8_t*)&fbuf[0][frow_s][fcol_s]     = f0;
        *(half8_t*)&fbuf[0][frow_s][fcol_s + 8] = f1;
        *(half8_t*)&hbuf[0][hrow_s][hcol_s]      = h0;
        *(half8_t*)&hbuf[0][hrow_s][32 + hcol_s] = h1;
    }
    __syncthreads();

    for (int t = 0; t < T; ++t) {
        const int buf = t & 1;
        const bool pf = (t + 1 < T);
        half8_t pf0, pf1, ph0, ph1;
        if (pf) {
            const _Float16* fsrc = fchunk + (size_t)((t + 1) * 64 + frow_s) * CC + fcol_s;
            const _Float16* hsrc = hchunk + (size_t)(t + 1) * 4096 + tid * 8;
            pf0 = *(const half8_t*)(fsrc);
            pf1 = *(const half8_t*)(fsrc + 8);
            ph0 = *(const half8_t*)(hsrc);
            ph1 = *(const half8_t*)(hsrc + 2048);
        }

#pragma unroll
        for (int ih = 0; ih < 2; ++ih) {
            f32x16 s0;
#pragma unroll
            for (int rb = 0; rb < 4; ++rb) {
                const f32x4 n4 = *(const f32x4*)(nb + t * 64 + ih * 32 + rb * 8 + q5 * 4);
#pragma unroll
                for (int k = 0; k < 4; ++k) s0[rb * 4 + k] = n4[k];
            }
            f32x16 s1 = s0;
            const _Float16* frow = &fbuf[buf][ih * 32 + l31][0] + q5 * 8;
#pragma unroll
            for (int kc = 0; kc < 4; ++kc) {
                const half8_t af = *(const half8_t*)(frow + kc * 16);
                s0 = __builtin_amdgcn_mfma_f32_32x32x16_f16(af, bg[0][kc], s0, 0, 0, 0);
                s1 = __builtin_amdgcn_mfma_f32_32x32x16_f16(af, bg[1][kc], s1, 0, 0, 0);
            }

            half8_t B[2][2];
#pragma unroll
            for (int jt = 0; jt < 2; ++jt) {
                const f32x16& s = jt ? s1 : s0;
                int e[8];
#pragma unroll
                for (int r8 = 0; r8 < 8; ++r8) {
                    e[r8] = __builtin_bit_cast(int, __builtin_amdgcn_cvt_pkrtz(
                        __builtin_exp2f(s[r8 * 2]), __builtin_exp2f(s[r8 * 2 + 1])));
                }
                const int sA = q5 ? e[0] : e[2];
                const int sB = q5 ? e[1] : e[3];
                const int sC = q5 ? e[4] : e[6];
                const int sD = q5 ? e[5] : e[7];
                const int rA = __shfl_xor(sA, 32, 64);
                const int rB = __shfl_xor(sB, 32, 64);
                const int rC = __shfl_xor(sC, 32, 64);
                const int rD = __shfl_xor(sD, 32, 64);
                int4v b0, b1;
                b0[0] = q5 ? rA   : e[0];
                b0[1] = q5 ? rB   : e[1];
                b0[2] = q5 ? e[2] : rA;
                b0[3] = q5 ? e[3] : rB;
                b1[0] = q5 ? rC   : e[4];
                b1[1] = q5 ? rD   : e[5];
                b1[2] = q5 ? e[6] : rC;
                b1[3] = q5 ? e[7] : rD;
                B[jt][0] = __builtin_bit_cast(half8_t, b0);
                B[jt][1] = __builtin_bit_cast(half8_t, b1);
            }

#pragma unroll
            for (int ct = 0; ct < 2; ++ct) {
                const half8_t ah0 = *(const half8_t*)(&hbuf[buf][ct * 32 + l31][0] + ih * 32 + q5 * 8);
                const half8_t ah1 = *(const half8_t*)(&hbuf[buf][ct * 32 + l31][0] + ih * 32 + 16 + q5 * 8);
                acc[0][ct] = __builtin_amdgcn_mfma_f32_32x32x16_f16(ah0, B[0][0], acc[0][ct], 0, 0, 0);
                acc[0][ct] = __builtin_amdgcn_mfma_f32_32x32x16_f16(ah1, B[0][1], acc[0][ct], 0, 0, 0);
                acc[1][ct] = __builtin_amdgcn_mfma_f32_32x32x16_f16(ah0, B[1][0], acc[1][ct], 0, 0, 0);
                acc[1][ct] = __builtin_amdgcn_mfma_f32_32x32x16_f16(ah1, B[1][1], acc[1][ct], 0, 0, 0);
            }
        }

        if (pf) {
            *(half8_t*)&fbuf[buf ^ 1][frow_s][fcol_s]     = pf0;
            *(half8_t*)&fbuf[buf ^ 1][frow_s][fcol_s + 8] = pf1;
            *(half8_t*)&hbuf[buf ^ 1][hrow_s][hcol_s]      = ph0;
            *(half8_t*)&hbuf[buf ^ 1][hrow_s][32 + hcol_s] = ph1;
        }
        __syncthreads();
    }

    _Float16* pb_out = pout + (((size_t)ic * BB + b) * CC) * NN;
#pragma unroll
    for (int jt = 0; jt < 2; ++jt) {
        const int j = jbase + jt * 32 + l31;
#pragma unroll
        for (int ct = 0; ct < 2; ++ct) {
#pragma unroll
            for (int r = 0; r < 16; ++r) {
                const int c = ct * 32 + (r & 3) + 8 * (r >> 2) + 4 * q5;
                pb_out[(size_t)c * NN + j] = (_Float16)acc[jt][ct][r];
            }
        }
    }
}

// ---------------------------------------------------------------------------
// Kernel D: out = gamma * sum_ic pout[ic] + x.
// ---------------------------------------------------------------------------
__global__ __launch_bounds__(256) void combine_kernel(
    const float* __restrict__ x, const float* __restrict__ gammap,
    const _Float16* __restrict__ pout, float* __restrict__ out)
{
    const float gam = gammap[0];
    const size_t i8 = ((size_t)blockIdx.x * 256 + threadIdx.x) * 8;
    const size_t TOT = (size_t)BB * CC * NN;

    float s[8] = {0.f, 0.f, 0.f, 0.f, 0.f, 0.f, 0.f, 0.f};
#pragma unroll
    for (int ic = 0; ic < NIC; ++ic) {
        const half8_t p = *(const half8_t*)(pout + ic * TOT + i8);
#pragma unroll
        for (int k = 0; k < 8; ++k) s[k] += (float)p[k];
    }
    const f32x4 x0 = *(const f32x4*)(x + i8);
    const f32x4 x1 = *(const f32x4*)(x + i8 + 4);
    f32x4 o0, o1;
#pragma unroll
    for (int k = 0; k < 4; ++k) { o0[k] = gam * s[k] + x0[k]; o1[k] = gam * s[k + 4] + x1[k]; }
    *(f32x4*)(out + i8) = o0;
    *(f32x4*)(out + i8 + 4) = o1;
}

// ---------------------------------------------------------------------------
extern "C" void kernel_launch(void* const* d_in, const int* in_sizes, int n_in,
                              void* d_out, int out_size, void* d_ws, size_t ws_size,
                              hipStream_t stream) {
    const float* x     = (const float*)d_in[0];
    const float* Wf    = (const float*)d_in[1];
    const float* bf    = (const float*)d_in[2];
    const float* Wg    = (const float*)d_in[3];
    const float* bg    = (const float*)d_in[4];
    const float* Wh    = (const float*)d_in[5];
    const float* bh    = (const float*)d_in[6];
    const float* gamma = (const float*)d_in[7];
    float* out = (float*)d_out;

    const size_t TOT = (size_t)BB * CC * NN;        // 2M elems
    _Float16* fT   = (_Float16*)d_ws;               // 4 MB
    _Float16* gT   = fT + TOT;                      // 4 MB
    _Float16* hT   = gT + TOT;                      // 4 MB
    _Float16* pout = hT + TOT;                      // NIC * 4 MB
    float* lpart   = (float*)(pout + (size_t)NIC * TOT);  // 1 MB
    float* nbias   = lpart + (size_t)JCH * BB * NN;       // 128 KB

    qkv_kernel<<<dim3(NN / 64, BB), 256, 0, stream>>>(
        x, Wf, bf, Wg, bg, Wh, bh, fT, gT, hT);
    stats_kernel<<<dim3(NN / 256, BB, JCH), 256, 0, stream>>>(fT, gT, lpart);
    rmerge_kernel<<<dim3(BB * NN / 256), 256, 0, stream>>>(lpart, nbias);
    attn_kernel<<<dim3(NN / 256, BB, NIC), 256, 0, stream>>>(fT, gT, hT, nbias, pout);
    combine_kernel<<<dim3(TOT / (256 * 8)), 256, 0, stream>>>(x, gamma, pout, out);
}

// Round 15
// 171.126 us; speedup vs baseline: 1.0618x; 1.0618x over previous
//
#include <hip/hip_runtime.h>

#define BB 8
#define CC 64
#define NN 4096
#define NIC 4            // i-chunks in attn pass
#define JCH 8            // j-chunks in stats pass
#define LOG2E 1.4426950408889634f

typedef float f32x4  __attribute__((ext_vector_type(4)));
typedef float f32x16 __attribute__((ext_vector_type(16)));
typedef _Float16 half8_t __attribute__((ext_vector_type(8)));
typedef int int4v __attribute__((ext_vector_type(4)));

// 32x32x16 f16 MFMA layouts (gfx950):
//   A[m][k]: m = lane&31, k = (lane>>5)*8 + idx   (8 halves)
//   B[k][n]: n = lane&31, k = (lane>>5)*8 + idx
//   C/D:     col = lane&31, row = (reg&3) + 8*(reg>>2) + 4*(lane>>5)
// A and B fragment layouts are IDENTICAL — swapping operand order transposes
// which index (reg vs lane) carries M — exploited in qkv.

// ---------------------------------------------------------------------------
// Kernel A: fused 1x1-conv QKV via MFMA. grid (NN/32, B), block 384 (6 waves).
// 32-px tile staged + f16-converted once; SIX chains = {f,g,h} x {ot0,ot1},
// exactly one chain per wave — perfect balance, 4 blocks/CU (24 waves/CU).
// f/g: D = mfma(xf, wf) -> col=o, row=px.  h: D = mfma(wf, xf) -> col=px.
// ---------------------------------------------------------------------------
__global__ __launch_bounds__(384, 6) void qkv_kernel(
    const float* __restrict__ x,
    const float* __restrict__ Wf, const float* __restrict__ bf,
    const float* __restrict__ Wg, const float* __restrict__ bg,
    const float* __restrict__ Wh, const float* __restrict__ bh,
    _Float16* __restrict__ fT, _Float16* __restrict__ gT,
    _Float16* __restrict__ hT)
{
    __shared__ float xbuf[64][36];         // 9.2 KB, stride 36 floats

    const int tid  = threadIdx.x;
    const int lane = tid & 63;
    const int wv   = tid >> 6;             // 0..5
    const int l31  = lane & 31;
    const int q5   = lane >> 5;
    const int z    = wv >> 1;              // 0=f 1=g 2=h
    const int ot   = wv & 1;               // o-tile
    const int n0   = blockIdx.x * 32;
    const int b    = blockIdx.y;

    // ---- stage x tile: 64 c-rows x 32 px, first 256 threads, 32 B each ----
    if (tid < 256) {
        const int row = tid >> 2;
        const int px4 = (tid & 3) * 8;
        const float* src = x + (size_t)(b * CC + row) * NN + n0 + px4;
        *(f32x4*)&xbuf[row][px4]     = *(const f32x4*)(src);
        *(f32x4*)&xbuf[row][px4 + 4] = *(const f32x4*)(src + 4);
    }
    __syncthreads();

    // ---- x-frag (m/n = px = l31), same for all waves ----
    half8_t xf[4];
#pragma unroll
    for (int kc = 0; kc < 4; ++kc) {
        const int kb = kc * 16 + q5 * 8;
        int4v p;
#pragma unroll
        for (int h2 = 0; h2 < 4; ++h2) {
            p[h2] = __builtin_bit_cast(int, __builtin_amdgcn_cvt_pkrtz(
                xbuf[kb + h2 * 2][l31], xbuf[kb + h2 * 2 + 1][l31]));
        }
        xf[kc] = __builtin_bit_cast(half8_t, p);
    }

    const float* W    = (z == 0) ? Wf : ((z == 1) ? Wg : Wh);
    const float* bias = (z == 0) ? bf : ((z == 1) ? bg : bh);

    // ---- W-frag (m/n = o = ot*32+l31) ----
    half8_t wf[4];
    {
        const float* wrow = W + (size_t)(ot * 32 + l31) * CC;
#pragma unroll
        for (int kc = 0; kc < 4; ++kc) {
            const f32x4 w0 = *(const f32x4*)(wrow + kc * 16 + q5 * 8);
            const f32x4 w1 = *(const f32x4*)(wrow + kc * 16 + q5 * 8 + 4);
            int4v p;
            p[0] = __builtin_bit_cast(int, __builtin_amdgcn_cvt_pkrtz(w0[0], w0[1]));
            p[1] = __builtin_bit_cast(int, __builtin_amdgcn_cvt_pkrtz(w0[2], w0[3]));
            p[2] = __builtin_bit_cast(int, __builtin_amdgcn_cvt_pkrtz(w1[0], w1[1]));
            p[3] = __builtin_bit_cast(int, __builtin_amdgcn_cvt_pkrtz(w1[2], w1[3]));
            wf[kc] = __builtin_bit_cast(half8_t, p);
        }
    }

    if (z < 2) {
        f32x16 acc = {};
#pragma unroll
        for (int kc = 0; kc < 4; ++kc)
            acc = __builtin_amdgcn_mfma_f32_32x32x16_f16(xf[kc], wf[kc], acc, 0, 0, 0);
        // D: col(lane)=o_local, row(reg)=px_local
        _Float16* dstT = (z == 0) ? fT : gT;
        const float scale = (z == 0) ? LOG2E : 1.0f;
        const float bv = bias[ot * 32 + l31];
#pragma unroll
        for (int r = 0; r < 16; ++r) {
            const int prow = (r & 3) + 8 * (r >> 2) + 4 * q5;
            dstT[(size_t)(b * NN + n0 + prow) * CC + ot * 32 + l31] =
                (_Float16)((acc[r] + bv) * scale);
        }
    } else {
        f32x16 acc = {};
#pragma unroll
        for (int kc = 0; kc < 4; ++kc)
            acc = __builtin_amdgcn_mfma_f32_32x32x16_f16(wf[kc], xf[kc], acc, 0, 0, 0);
        // D: col(lane)=px_local, row(reg)=o_local; one 32-px h tile per block
        _Float16* hbase = hT + ((size_t)(b * (NN / 32) + blockIdx.x) * CC) * 32;
#pragma unroll
        for (int rb = 0; rb < 4; ++rb) {
            const f32x4 b4 = *(const f32x4*)(bias + ot * 32 + rb * 8 + q5 * 4);
#pragma unroll
            for (int k = 0; k < 4; ++k) {
                const int c = ot * 32 + rb * 8 + q5 * 4 + k;
                hbase[(size_t)c * 32 + l31] = (_Float16)(acc[rb * 4 + k] + b4[k]);
            }
        }
    }
}

// ---------------------------------------------------------------------------
// Kernel B: partial row sums of exp2(logits). grid (NN/128, B, JCH), block 256.
// R13-proven structure (wave i-tile 32, 1-deep register prefetch).
// ---------------------------------------------------------------------------
__global__ __launch_bounds__(256, 4) void stats_kernel(
    const _Float16* __restrict__ fT, const _Float16* __restrict__ gT,
    float* __restrict__ lpart)
{
    __shared__ _Float16 gbuf[2][64][72];   // stride 72 halves

    const int lane = threadIdx.x & 63;
    const int wv   = threadIdx.x >> 6;
    const int b    = blockIdx.y;
    const int jc   = blockIdx.z;
    const int i0   = blockIdx.x * 128 + wv * 32;
    const int l31  = lane & 31;
    const int q5   = lane >> 5;

    half8_t a[4];
    const _Float16* fa = fT + (size_t)(b * NN + i0 + l31) * CC + q5 * 8;
#pragma unroll
    for (int kc = 0; kc < 4; ++kc) a[kc] = *(const half8_t*)(fa + kc * 16);

    const _Float16* gchunk = gT + (size_t)(b * NN + jc * (NN / JCH)) * CC;
    const int T = NN / JCH / 64;   // 8 tiles of 64 j

    const int srow = wv * 16 + (lane >> 3);
    const int scol = (lane & 7) * 8;

    {   // stage tile 0
        const half8_t v0 = *(const half8_t*)(gchunk + (size_t)srow * CC + scol);
        const half8_t v1 = *(const half8_t*)(gchunk + (size_t)(srow + 8) * CC + scol);
        *(half8_t*)&gbuf[0][srow][scol] = v0;
        *(half8_t*)&gbuf[0][srow + 8][scol] = v1;
    }
    __syncthreads();

    float l16[16];
#pragma unroll
    for (int r = 0; r < 16; ++r) l16[r] = 0.f;

    for (int t = 0; t < T; ++t) {
        const int buf = t & 1;
        const bool pf = (t + 1 < T);
        half8_t p0, p1;
        if (pf) {
            const _Float16* src = gchunk + (size_t)((t + 1) * 64 + srow) * CC + scol;
            p0 = *(const half8_t*)(src);
            p1 = *(const half8_t*)(src + 8 * CC);
        }
#pragma unroll
        for (int js = 0; js < 2; ++js) {
            const _Float16* grow = &gbuf[buf][js * 32 + l31][0] + q5 * 8;
            f32x16 s = {};
#pragma unroll
            for (int kc = 0; kc < 4; ++kc) {
                const half8_t bfr = *(const half8_t*)(grow + kc * 16);
                s = __builtin_amdgcn_mfma_f32_32x32x16_f16(a[kc], bfr, s, 0, 0, 0);
            }
#pragma unroll
            for (int r = 0; r < 16; ++r) l16[r] += __builtin_exp2f(s[r]);
        }
        if (pf) {
            *(half8_t*)&gbuf[buf ^ 1][srow][scol] = p0;
            *(half8_t*)&gbuf[buf ^ 1][srow + 8][scol] = p1;
        }
        __syncthreads();
    }

#pragma unroll
    for (int r = 0; r < 16; ++r) {
#pragma unroll
        for (int off = 1; off < 32; off <<= 1)
            l16[r] += __shfl_xor(l16[r], off);
    }

    if (l31 == 0) {
        float* lp = lpart + (size_t)jc * BB * NN + b * NN + i0;
#pragma unroll
        for (int rb = 0; rb < 4; ++rb) {
            f32x4 v;
#pragma unroll
            for (int k = 0; k < 4; ++k) v[k] = l16[rb * 4 + k];
            *(f32x4*)(lp + rb * 8 + q5 * 4) = v;
        }
    }
}

// ---------------------------------------------------------------------------
// Kernel C: partial out chunks. grid (NN/256, B, NIC), block 256.
// R12 structure (wave j-tile 64, 1-deep register prefetch) + FUSED RMERGE:
// each block computes its i-chunk's nbias = -log2(sum_jc lpart) into LDS in
// the prologue (identical jc-sum order -> bit-identical to the old rmerge).
// ---------------------------------------------------------------------------
__global__ __launch_bounds__(256, 2) void attn_kernel(
    const _Float16* __restrict__ fT, const _Float16* __restrict__ gT,
    const _Float16* __restrict__ hT, const float* __restrict__ lpart,
    _Float16* __restrict__ pout)
{
    __shared__ _Float16 fbuf[2][64][72];   // 18.4 KB
    __shared__ _Float16 hbuf[2][64][72];   // 18.4 KB
    __shared__ float nbbuf[NN / NIC];      // 4 KB

    const int lane = threadIdx.x & 63;
    const int wv   = threadIdx.x >> 6;
    const int b    = blockIdx.y;
    const int ic   = blockIdx.z;
    const int l31  = lane & 31;
    const int q5   = lane >> 5;
    const int jbase = blockIdx.x * 256 + wv * 64;

    const int ichunk = NN / NIC;           // 1024
    const int ibase  = ic * ichunk;
    const int tid    = threadIdx.x;

    // ---- fused rmerge: nbias for this i-chunk (4 values/thread) ----
    {
        const float* lp0 = lpart + b * NN + ibase + tid * 4;
        f32x4 sum = *(const f32x4*)(lp0);
#pragma unroll
        for (int jc = 1; jc < JCH; ++jc) {
            const f32x4 v = *(const f32x4*)(lp0 + (size_t)jc * BB * NN);
#pragma unroll
            for (int k = 0; k < 4; ++k) sum[k] += v[k];
        }
        f32x4 nb4;
#pragma unroll
        for (int k = 0; k < 4; ++k) nb4[k] = -__builtin_log2f(sum[k]);
        *(f32x4*)&nbbuf[tid * 4] = nb4;
    }

    half8_t bg[2][4];
#pragma unroll
    for (int jt = 0; jt < 2; ++jt) {
        const _Float16* grow = gT + (size_t)(b * NN + jbase + jt * 32 + l31) * CC + q5 * 8;
#pragma unroll
        for (int kc = 0; kc < 4; ++kc) bg[jt][kc] = *(const half8_t*)(grow + kc * 16);
    }

    f32x16 acc[2][2] = {};   // [jt][ct]

    const _Float16* fchunk = fT + ((size_t)b * NN + ibase) * CC;
    const _Float16* hchunk = hT + ((size_t)(b * (NN / 32) + ibase / 32) * CC) * 32;
    const int T = ichunk / 64;             // 16 iterations

    const int frow_s = tid >> 2;            // 0..63
    const int fcol_s = (tid & 3) * 16;
    const int hrow_s = tid >> 2;
    const int hcol_s = (tid & 3) * 8;

    {   // stage tile 0
        const half8_t f0 = *(const half8_t*)(fchunk + (size_t)frow_s * CC + fcol_s);
        const half8_t f1 = *(const half8_t*)(fchunk + (size_t)frow_s * CC + fcol_s + 8);
        const half8_t h0 = *(const half8_t*)(hchunk + tid * 8);
        const half8_t h1 = *(const half8_t*)(hchunk + 2048 + tid * 8);
        *(half8_t*)&fbuf[0][frow_s][fcol_s]     = f0;
        *(half8_t*)&fbuf[0][frow_s][fcol_s + 8] = f1;
        *(half8_t*)&hbuf[0][hrow_s][hcol_s]      = h0;
        *(half8_t*)&hbuf[0][hrow_s][32 + hcol_s] = h1;
    }
    __syncthreads();

    for (int t = 0; t < T; ++t) {
        const int buf = t & 1;
        const bool pf = (t + 1 < T);
        half8_t pf0, pf1, ph0, ph1;
        if (pf) {
            const _Float16* fsrc = fchunk + (size_t)((t + 1) * 64 + frow_s) * CC + fcol_s;
            const _Float16* hsrc = hchunk + (size_t)(t + 1) * 4096 + tid * 8;
            pf0 = *(const half8_t*)(fsrc);
            pf1 = *(const half8_t*)(fsrc + 8);
            ph0 = *(const half8_t*)(hsrc);
            ph1 = *(const half8_t*)(hsrc + 2048);
        }

#pragma unroll
        for (int ih = 0; ih < 2; ++ih) {
            f32x16 s0;
#pragma unroll
            for (int rb = 0; rb < 4; ++rb) {
                const f32x4 n4 = *(const f32x4*)&nbbuf[t * 64 + ih * 32 + rb * 8 + q5 * 4];
#pragma unroll
                for (int k = 0; k < 4; ++k) s0[rb * 4 + k] = n4[k];
            }
            f32x16 s1 = s0;
            const _Float16* frow = &fbuf[buf][ih * 32 + l31][0] + q5 * 8;
#pragma unroll
            for (int kc = 0; kc < 4; ++kc) {
                const half8_t af = *(const half8_t*)(frow + kc * 16);
                s0 = __builtin_amdgcn_mfma_f32_32x32x16_f16(af, bg[0][kc], s0, 0, 0, 0);
                s1 = __builtin_amdgcn_mfma_f32_32x32x16_f16(af, bg[1][kc], s1, 0, 0, 0);
            }

            half8_t B[2][2];
#pragma unroll
            for (int jt = 0; jt < 2; ++jt) {
                const f32x16& s = jt ? s1 : s0;
                int e[8];
#pragma unroll
                for (int r8 = 0; r8 < 8; ++r8) {
                    e[r8] = __builtin_bit_cast(int, __builtin_amdgcn_cvt_pkrtz(
                        __builtin_exp2f(s[r8 * 2]), __builtin_exp2f(s[r8 * 2 + 1])));
                }
                const int sA = q5 ? e[0] : e[2];
                const int sB = q5 ? e[1] : e[3];
                const int sC = q5 ? e[4] : e[6];
                const int sD = q5 ? e[5] : e[7];
                const int rA = __shfl_xor(sA, 32, 64);
                const int rB = __shfl_xor(sB, 32, 64);
                const int rC = __shfl_xor(sC, 32, 64);
                const int rD = __shfl_xor(sD, 32, 64);
                int4v b0, b1;
                b0[0] = q5 ? rA   : e[0];
                b0[1] = q5 ? rB   : e[1];
                b0[2] = q5 ? e[2] : rA;
                b0[3] = q5 ? e[3] : rB;
                b1[0] = q5 ? rC   : e[4];
                b1[1] = q5 ? rD   : e[5];
                b1[2] = q5 ? e[6] : rC;
                b1[3] = q5 ? e[7] : rD;
                B[jt][0] = __builtin_bit_cast(half8_t, b0);
                B[jt][1] = __builtin_bit_cast(half8_t, b1);
            }

#pragma unroll
            for (int ct = 0; ct < 2; ++ct) {
                const half8_t ah0 = *(const half8_t*)(&hbuf[buf][ct * 32 + l31][0] + ih * 32 + q5 * 8);
                const half8_t ah1 = *(const half8_t*)(&hbuf[buf][ct * 32 + l31][0] + ih * 32 + 16 + q5 * 8);
                acc[0][ct] = __builtin_amdgcn_mfma_f32_32x32x16_f16(ah0, B[0][0], acc[0][ct], 0, 0, 0);
                acc[0][ct] = __builtin_amdgcn_mfma_f32_32x32x16_f16(ah1, B[0][1], acc[0][ct], 0, 0, 0);
                acc[1][ct] = __builtin_amdgcn_mfma_f32_32x32x16_f16(ah0, B[1][0], acc[1][ct], 0, 0, 0);
                acc[1][ct] = __builtin_amdgcn_mfma_f32_32x32x16_f16(ah1, B[1][1], acc[1][ct], 0, 0, 0);
            }
        }

        if (pf) {
            *(half8_t*)&fbuf[buf ^ 1][frow_s][fcol_s]     = pf0;
            *(half8_t*)&fbuf[buf ^ 1][frow_s][fcol_s + 8] = pf1;
            *(half8_t*)&hbuf[buf ^ 1][hrow_s][hcol_s]      = ph0;
            *(half8_t*)&hbuf[buf ^ 1][hrow_s][32 + hcol_s] = ph1;
        }
        __syncthreads();
    }

    _Float16* pb_out = pout + (((size_t)ic * BB + b) * CC) * NN;
#pragma unroll
    for (int jt = 0; jt < 2; ++jt) {
        const int j = jbase + jt * 32 + l31;
#pragma unroll
        for (int ct = 0; ct < 2; ++ct) {
#pragma unroll
            for (int r = 0; r < 16; ++r) {
                const int c = ct * 32 + (r & 3) + 8 * (r >> 2) + 4 * q5;
                pb_out[(size_t)c * NN + j] = (_Float16)acc[jt][ct][r];
            }
        }
    }
}

// ---------------------------------------------------------------------------
// Kernel D: out = gamma * sum_ic pout[ic] + x.
// ---------------------------------------------------------------------------
__global__ __launch_bounds__(256) void combine_kernel(
    const float* __restrict__ x, const float* __restrict__ gammap,
    const _Float16* __restrict__ pout, float* __restrict__ out)
{
    const float gam = gammap[0];
    const size_t i8 = ((size_t)blockIdx.x * 256 + threadIdx.x) * 8;
    const size_t TOT = (size_t)BB * CC * NN;

    float s[8] = {0.f, 0.f, 0.f, 0.f, 0.f, 0.f, 0.f, 0.f};
#pragma unroll
    for (int ic = 0; ic < NIC; ++ic) {
        const half8_t p = *(const half8_t*)(pout + ic * TOT + i8);
#pragma unroll
        for (int k = 0; k < 8; ++k) s[k] += (float)p[k];
    }
    const f32x4 x0 = *(const f32x4*)(x + i8);
    const f32x4 x1 = *(const f32x4*)(x + i8 + 4);
    f32x4 o0, o1;
#pragma unroll
    for (int k = 0; k < 4; ++k) { o0[k] = gam * s[k] + x0[k]; o1[k] = gam * s[k + 4] + x1[k]; }
    *(f32x4*)(out + i8) = o0;
    *(f32x4*)(out + i8 + 4) = o1;
}

// ---------------------------------------------------------------------------
extern "C" void kernel_launch(void* const* d_in, const int* in_sizes, int n_in,
                              void* d_out, int out_size, void* d_ws, size_t ws_size,
                              hipStream_t stream) {
    const float* x     = (const float*)d_in[0];
    const float* Wf    = (const float*)d_in[1];
    const float* bf    = (const float*)d_in[2];
    const float* Wg    = (const float*)d_in[3];
    const float* bg    = (const float*)d_in[4];
    const float* Wh    = (const float*)d_in[5];
    const float* bh    = (const float*)d_in[6];
    const float* gamma = (const float*)d_in[7];
    float* out = (float*)d_out;

    const size_t TOT = (size_t)BB * CC * NN;        // 2M elems
    _Float16* fT   = (_Float16*)d_ws;               // 4 MB
    _Float16* gT   = fT + TOT;                      // 4 MB
    _Float16* hT   = gT + TOT;                      // 4 MB
    _Float16* pout = hT + TOT;                      // NIC * 4 MB
    float* lpart   = (float*)(pout + (size_t)NIC * TOT);  // 1 MB

    qkv_kernel<<<dim3(NN / 32, BB), 384, 0, stream>>>(
        x, Wf, bf, Wg, bg, Wh, bh, fT, gT, hT);
    stats_kernel<<<dim3(NN / 128, BB, JCH), 256, 0, stream>>>(fT, gT, lpart);
    attn_kernel<<<dim3(NN / 256, BB, NIC), 256, 0, stream>>>(fT, gT, hT, lpart, pout);
    combine_kernel<<<dim3(TOT / (256 * 8)), 256, 0, stream>>>(x, gamma, pout, out);
}